// Round 3
// baseline (145.412 us; speedup 1.0000x reference)
//
#include <hip/hip_runtime.h>
#include <math.h>

// ClownSelector R12: single-buffered LDS + depth-1 ds_read rotation.
//
// R11 post-mortem: LDS-staged proto won (57->48us) but LDS came out 103KB
// (xt 37K + pt 65K + nq 1K) -> 1 block/CU = 2 waves/SIMD; VALUBusy 32%.
// Issue-floor arithmetic: 2 waves x 128 ksteps x 64cyc x 2 rounds = 14.6us;
// measured 48us <=> ~150cyc stall/kstep = exposed ds_read latency (~120cyc)
// with 2 waves/SIMD and VGPR=124 pinning the scheduler at the 128 cliff.
// LDS pipe is NOT the bound: every b128 read here is 8 addrs x 8-way
// broadcast = 128B of banks (~2cyc) vs 64cyc of fmac.
//
// R12: (1) single-buffer xt AND pt -- staging is wave-private and the DS
// pipe executes a wave's LDS ops in order, so WAR to the same buffer is
// hazard-free (same guarantee R9-R11 relied on). LDS 103.4KB -> 52.2KB ->
// 2 blocks/CU = 16 waves = 4 waves/SIMD. (2) depth-1 register rotation of
// the 3 ds_reads in the k-loop: reads for kk+1 issue before fmacs of kk,
// guaranteeing ~64cyc of cover per read even if the scheduler stays timid.
// (3) B0/B1/nq carved from one SMEM block; epilogue aliases dead xt region.
// Tile, staging patterns, reduction tree, K0, K2: R11-verified, unchanged.

#define BB 8
#define SS 2048
#define DD 1024
#define EE 64
#define EPSV 1e-8f

#define FMA4(A, s, P) \
  A.x += (s) * (P).x; A.y += (s) * (P).y; A.z += (s) * (P).z; A.w += (s) * (P).w;

#define SUMSQ4(v) ((v).x * (v).x + (v).y * (v).y + (v).z * (v).z + (v).w * (v).w)

// ---- K0: proto[e][d] -> ptt[d][e] -----------------------------------------
__global__ __launch_bounds__(256) void repack_proto(
    const float* __restrict__ proto, float* __restrict__ ptt) {
  const int gid = blockIdx.x * 256 + threadIdx.x;  // 0..65535
  const int d = gid >> 6;
  const int e = gid & 63;
  ptt[gid] = proto[(size_t)e * DD + d];
}

// ---- K1: normalized per-row dots ------------------------------------------
// SMEM layout (floats):
//   [    0 .. 4607]  xt: 8 waves x [16 k][36 tok-pad]   (single-buffered)
//   [ 4608 ..12799]  pt: 8 waves x [16 k][64 e]         (single-buffered)
//   [12800 ..13055]  nq: 8 waves x [32 tok]
// Epilogue aliases B0 = SMEM[0..2175], B1 = SMEM[2176..4351] (dead xt).
__global__ __launch_bounds__(512, 2) void router_dots(
    const float* __restrict__ x, const float* __restrict__ ptt,
    float* __restrict__ dots) {
  __shared__ float SMEM[13056];

  const int lane = threadIdx.x & 63;
  const int w    = __builtin_amdgcn_readfirstlane(threadIdx.x >> 6);  // 0..7
  const int b    = blockIdx.x >> 6;          // 64 blocks per batch
  const int s0   = (blockIdx.x & 63) * 32;   // 32 tokens per block

  const int toks = lane & 31;  // staging: token
  const int kh   = lane >> 5;  // staging: k-half (8 floats)
  const int eg   = lane & 7;   // tile: expert group (8 e)
  const int tg   = lane >> 3;  // tile: token group (4 t)

  float* xtw = SMEM + w * 576;           // [16][36]
  float* ptw = SMEM + 4608 + w * 1024;   // [16][64]
  float* nqp = SMEM + 12800;             // [8][32]

  const float* xb = x + ((size_t)b * SS + s0) * DD;
  const int kbase = w * 128;   // this wave's k-slice (128 wide)

  float4 acc0[4], acc1[4];
#pragma unroll
  for (int i = 0; i < 4; ++i) {
    acc0[i] = make_float4(0.f, 0.f, 0.f, 0.f);
    acc1[i] = make_float4(0.f, 0.f, 0.f, 0.f);
  }
  float q = 0.0f;

  // ---- prologue: stage chunk 0 (x + proto) ----
  {
    const float* xs = xb + (size_t)toks * DD + kbase + kh * 8;
    const float4 va = *(const float4*)(xs);
    const float4 vb = *(const float4*)(xs + 4);
    q += SUMSQ4(va) + SUMSQ4(vb);
    float* dstc = xtw + toks;
    dstc[(kh * 8 + 0) * 36] = va.x;
    dstc[(kh * 8 + 1) * 36] = va.y;
    dstc[(kh * 8 + 2) * 36] = va.z;
    dstc[(kh * 8 + 3) * 36] = va.w;
    dstc[(kh * 8 + 4) * 36] = vb.x;
    dstc[(kh * 8 + 5) * 36] = vb.y;
    dstc[(kh * 8 + 6) * 36] = vb.z;
    dstc[(kh * 8 + 7) * 36] = vb.w;

    const float* ps = ptt + (size_t)kbase * EE;
    const float4 q0 = *(const float4*)(ps + lane * 4);
    const float4 q1 = *(const float4*)(ps + 256 + lane * 4);
    const float4 q2 = *(const float4*)(ps + 512 + lane * 4);
    const float4 q3 = *(const float4*)(ps + 768 + lane * 4);
    float* pd = ptw + lane * 4;
    *(float4*)(pd)       = q0;
    *(float4*)(pd + 256) = q1;
    *(float4*)(pd + 512) = q2;
    *(float4*)(pd + 768) = q3;
  }

  const float* xc = xtw + tg * 4;   // + kk*36
  const float* pc = ptw + eg * 8;   // + kk*64

  for (int c = 0; c < 8; ++c) {   // 8 chunks x 16 k = 128 k
    // ---- prefetch next chunk's x + proto (consumed after the k-loop) ----
    float4 na, nb, r0, r1, r2, r3;
    if (c + 1 < 8) {
      const float* xs = xb + (size_t)toks * DD + kbase + (c + 1) * 16 + kh * 8;
      na = *(const float4*)(xs);
      nb = *(const float4*)(xs + 4);
      const float* ps = ptt + (size_t)(kbase + (c + 1) * 16) * EE;
      r0 = *(const float4*)(ps + lane * 4);
      r1 = *(const float4*)(ps + 256 + lane * 4);
      r2 = *(const float4*)(ps + 512 + lane * 4);
      r3 = *(const float4*)(ps + 768 + lane * 4);
    }
    // ---- 16 k-steps, depth-1 LDS rotation: read kk+1 before fmacs of kk ----
    float4 xf = *(const float4*)(xc);
    float4 p0 = *(const float4*)(pc);
    float4 p1 = *(const float4*)(pc + 4);
#pragma unroll
    for (int kk = 0; kk < 16; ++kk) {
      const int nk = (kk + 1) & 15;   // kk=15 re-reads row 0 (discarded)
      const float4 xfn = *(const float4*)(xc + nk * 36);
      const float4 p0n = *(const float4*)(pc + nk * 64);
      const float4 p1n = *(const float4*)(pc + nk * 64 + 4);
      FMA4(acc0[0], xf.x, p0) FMA4(acc1[0], xf.x, p1)
      FMA4(acc0[1], xf.y, p0) FMA4(acc1[1], xf.y, p1)
      FMA4(acc0[2], xf.z, p0) FMA4(acc1[2], xf.z, p1)
      FMA4(acc0[3], xf.w, p0) FMA4(acc1[3], xf.w, p1)
      xf = xfn; p0 = p0n; p1 = p1n;
    }
    // ---- stage prefetched chunk (same buffers; wave-private DS in-order) ----
    if (c + 1 < 8) {
      q += SUMSQ4(na) + SUMSQ4(nb);
      float* dstc = xtw + toks;
      dstc[(kh * 8 + 0) * 36] = na.x;
      dstc[(kh * 8 + 1) * 36] = na.y;
      dstc[(kh * 8 + 2) * 36] = na.z;
      dstc[(kh * 8 + 3) * 36] = na.w;
      dstc[(kh * 8 + 4) * 36] = nb.x;
      dstc[(kh * 8 + 5) * 36] = nb.y;
      dstc[(kh * 8 + 6) * 36] = nb.z;
      dstc[(kh * 8 + 7) * 36] = nb.w;
      float* pd = ptw + lane * 4;
      *(float4*)(pd)       = r0;
      *(float4*)(pd + 256) = r1;
      *(float4*)(pd + 512) = r2;
      *(float4*)(pd + 768) = r3;
    }
  }

  // sumsq: combine the two k-halves of each token; kh==0 lanes publish
  q += __shfl_xor(q, 32);
  if (kh == 0) nqp[w * 32 + toks] = q;

  // epilogue reduction buffers alias the (now dead) xt region
  float (*B0)[68] = reinterpret_cast<float (*)[68]>(SMEM);
  float (*B1)[68] = reinterpret_cast<float (*)[68]>(SMEM + 2176);

#define WRB(R)                                                  \
  { _Pragma("unroll") for (int i = 0; i < 4; ++i) {             \
      *(float4*)(&(R)[tg * 4 + i][eg * 8])     = acc0[i];       \
      *(float4*)(&(R)[tg * 4 + i][eg * 8 + 4]) = acc1[i]; } }
#define ADDB(R)                                                 \
  { _Pragma("unroll") for (int i = 0; i < 4; ++i) {             \
      const float4 t0 = *(const float4*)(&(R)[tg * 4 + i][eg * 8]);     \
      const float4 t1 = *(const float4*)(&(R)[tg * 4 + i][eg * 8 + 4]); \
      acc0[i].x += t0.x; acc0[i].y += t0.y;                     \
      acc0[i].z += t0.z; acc0[i].w += t0.w;                     \
      acc1[i].x += t1.x; acc1[i].y += t1.y;                     \
      acc1[i].z += t1.z; acc1[i].w += t1.w; } }

  // deterministic tree over 8 waves: pairwise (w, w+1) -> (w, w+2) -> (w, w+4)
  __syncthreads();
  if (w == 1) WRB(B0)
  if (w == 5) WRB(B1)
  __syncthreads();
  if (w == 0) ADDB(B0)
  if (w == 4) ADDB(B1)
  __syncthreads();
  if (w == 3) WRB(B0)
  if (w == 7) WRB(B1)
  __syncthreads();
  if (w == 2) ADDB(B0)
  if (w == 6) ADDB(B1)
  __syncthreads();
  if (w == 2) WRB(B0)
  if (w == 6) WRB(B1)
  __syncthreads();
  if (w == 0) ADDB(B0)
  if (w == 4) ADDB(B1)
  __syncthreads();
  if (w == 4) WRB(B0)
  __syncthreads();
  if (w == 0) {
    ADDB(B0)
#pragma unroll
    for (int i = 0; i < 4; ++i) {
      const int row = tg * 4 + i;
      const float qs = nqp[0 * 32 + row] + nqp[1 * 32 + row] +
                       nqp[2 * 32 + row] + nqp[3 * 32 + row] +
                       nqp[4 * 32 + row] + nqp[5 * 32 + row] +
                       nqp[6 * 32 + row] + nqp[7 * 32 + row];
      const float inv = 1.0f / fmaxf(sqrtf(qs), EPSV);
      float4 o0, o1;
      o0.x = acc0[i].x * inv; o0.y = acc0[i].y * inv;
      o0.z = acc0[i].z * inv; o0.w = acc0[i].w * inv;
      o1.x = acc1[i].x * inv; o1.y = acc1[i].y * inv;
      o1.z = acc1[i].z * inv; o1.w = acc1[i].w * inv;
      float* dp = dots + ((size_t)b * SS + s0 + row) * EE + eg * 8;
      *(float4*)(dp)     = o0;
      *(float4*)(dp + 4) = o1;
    }
  }
}

// ---- K2: window-3 + top-2 + renorm softmax (array-free, R7-verified) -------
#define T2UP(s, ei)                                            \
  if ((s) > v1) { v2 = v1; i2 = i1; v1 = (s); i1 = (ei); }     \
  else if ((s) > v2) { v2 = (s); i2 = (ei); }

__global__ __launch_bounds__(256) void router_top2(
    const float* __restrict__ dots, float* __restrict__ out) {
  const int gtid = blockIdx.x * 256 + threadIdx.x;  // 0..32767
  const int tok  = gtid >> 1;          // global token
  const int h    = gtid & 1;           // expert half (32 each)
  const int b    = tok >> 11;
  const int sl   = tok & (SS - 1);
  const int r0   = (sl >= 2) ? sl - 2 : 0;   // causal pad: replicate token 0
  const int r1   = (sl >= 1) ? sl - 1 : 0;

  const float* d0 = dots + ((size_t)b * SS + r0) * EE + h * 32;
  const float* d1 = dots + ((size_t)b * SS + r1) * EE + h * 32;
  const float* d2 = dots + ((size_t)b * SS + sl) * EE + h * 32;

  float v1 = -INFINITY, v2 = -INFINITY;
  int i1 = 0, i2 = 0;
#pragma unroll
  for (int qd = 0; qd < 8; ++qd) {
    const float4 a = *(const float4*)(d0 + qd * 4);
    const float4 c = *(const float4*)(d1 + qd * 4);
    const float4 e = *(const float4*)(d2 + qd * 4);
    const int e0 = h * 32 + qd * 4;
    float s;
    s = a.x + c.x + e.x; T2UP(s, e0 + 0)
    s = a.y + c.y + e.y; T2UP(s, e0 + 1)
    s = a.z + c.z + e.z; T2UP(s, e0 + 2)
    s = a.w + c.w + e.w; T2UP(s, e0 + 3)
  }

  {  // merge the two halves (partner lane = lane^1); tie -> lower index
    const float ov1 = __shfl_xor(v1, 1);
    const int   oi1 = __shfl_xor(i1, 1);
    const float ov2 = __shfl_xor(v2, 1);
    const int   oi2 = __shfl_xor(i2, 1);
    const bool o_beats = (ov1 > v1) || (ov1 == v1 && oi1 < i1);
    if (o_beats) {
      const bool v1_beats_o2 = (v1 > ov2) || (v1 == ov2 && i1 < oi2);
      v2 = v1_beats_o2 ? v1 : ov2;
      i2 = v1_beats_o2 ? i1 : oi2;
      v1 = ov1;
      i1 = oi1;
    } else {
      const bool o1_beats_v2 = (ov1 > v2) || (ov1 == v2 && oi1 < i2);
      if (o1_beats_v2) { v2 = ov1; i2 = oi1; }
    }
  }

  if (h == 0) {
    const float ex = expf((v2 - v1) * (1.0f / 3.0f));  // <= 1
    const float w1 = 1.0f / (1.0f + ex);
    const size_t o = (size_t)tok * 2;
    *(float2*)(out + o) = make_float2((float)i1, (float)i2);
    *(float2*)(out + (size_t)BB * SS * 2 + o) = make_float2(w1, ex * w1);
  }
}

extern "C" void kernel_launch(void* const* d_in, const int* in_sizes, int n_in,
                              void* d_out, int out_size, void* d_ws, size_t ws_size,
                              hipStream_t stream) {
  const float* x     = (const float*)d_in[0];
  const float* proto = (const float*)d_in[1];
  // d_in[2] = attn_mask: unused by the reference output path.
  float* out  = (float*)d_out;
  float* ptt  = (float*)d_ws;                          // 256 KiB ptt[d][e]
  float* dots = (float*)((char*)d_ws + (512 << 10));   // 4 MiB normalized dots

  repack_proto<<<dim3(256), dim3(256), 0, stream>>>(proto, ptt);
  router_dots<<<dim3(512), dim3(512), 0, stream>>>(x, ptt, dots);
  router_top2<<<dim3(128), dim3(256), 0, stream>>>(dots, out);
}

// Round 4
// 124.395 us; speedup vs baseline: 1.1690x; 1.1690x over previous
//
#include <hip/hip_runtime.h>
#include <math.h>

// ClownSelector R13: R11 structure + single-buffered pt. No rotation.
//
// R12 post-mortem: WRITE_SIZE 4->35.7MB = scratch spills (R8's smoking gun).
// The depth-1 rotation's 3 extra live float4s on top of the 6 prefetch
// float4s pushed the allocator past 128 -> spill; VALUBusy FELL to 24%.
// The occupancy move was right; the rotation was a register-pressure error.
//
// R13 combines the two separately-proven facts:
//  (a) R11's k-loop body compiles clean at VGPR 124, zero spills;
//  (b) single-buffered wave-private LDS staging is correct (R12 passed:
//      DS pipe executes a wave's LDS ops in order -> WAR hazard-free).
// => R11 verbatim, but pt single-buffered (the 65.5KB hog). xt stays
// double-buffered exactly as R11. LDS = 36,864 + 32,768 + 1,024 = 70,656 B
// -> 2 blocks/CU = 16 waves = 4 waves/SIMD (VGPR 124 <= 128 also admits 4).
// Epilogue B0/B1 alias the dead xt region, as R11/R12.

#define BB 8
#define SS 2048
#define DD 1024
#define EE 64
#define EPSV 1e-8f

#define FMA4(A, s, P) \
  A.x += (s) * (P).x; A.y += (s) * (P).y; A.z += (s) * (P).z; A.w += (s) * (P).w;

#define SUMSQ4(v) ((v).x * (v).x + (v).y * (v).y + (v).z * (v).z + (v).w * (v).w)

// ---- K0: proto[e][d] -> ptt[d][e] -----------------------------------------
__global__ __launch_bounds__(256) void repack_proto(
    const float* __restrict__ proto, float* __restrict__ ptt) {
  const int gid = blockIdx.x * 256 + threadIdx.x;  // 0..65535
  const int d = gid >> 6;
  const int e = gid & 63;
  ptt[gid] = proto[(size_t)e * DD + d];
}

// ---- K1: normalized per-row dots ------------------------------------------
__global__ __launch_bounds__(512, 2) void router_dots(
    const float* __restrict__ x, const float* __restrict__ ptt,
    float* __restrict__ dots) {
  __shared__ float xt[8][2][16][36];  // x chunks, double-buffered (R11 layout)
  __shared__ float pt[8][16][64];     // proto chunk, SINGLE-buffered
  __shared__ float nq[8][32];         // per-wave per-token sumsq partials

  const int lane = threadIdx.x & 63;
  const int w    = __builtin_amdgcn_readfirstlane(threadIdx.x >> 6);  // 0..7
  const int b    = blockIdx.x >> 6;          // 64 blocks per batch
  const int s0   = (blockIdx.x & 63) * 32;   // 32 tokens per block

  const int toks = lane & 31;  // staging: token
  const int kh   = lane >> 5;  // staging: k-half (8 floats)
  const int eg   = lane & 7;   // tile: expert group (8 e)
  const int tg   = lane >> 3;  // tile: token group (4 t)

  const float* xb = x + ((size_t)b * SS + s0) * DD;
  const int kbase = w * 128;   // this wave's k-slice (128 wide)

  float4 acc0[4], acc1[4];
#pragma unroll
  for (int i = 0; i < 4; ++i) {
    acc0[i] = make_float4(0.f, 0.f, 0.f, 0.f);
    acc1[i] = make_float4(0.f, 0.f, 0.f, 0.f);
  }
  float q = 0.0f;

  // ---- prologue: stage chunk 0 (x into buf 0, proto into pt) ----
  {
    const float* xs = xb + (size_t)toks * DD + kbase + kh * 8;
    const float4 va = *(const float4*)(xs);
    const float4 vb = *(const float4*)(xs + 4);
    q += SUMSQ4(va) + SUMSQ4(vb);
    float* dstc = &xt[w][0][0][toks];
    dstc[(kh * 8 + 0) * 36] = va.x;
    dstc[(kh * 8 + 1) * 36] = va.y;
    dstc[(kh * 8 + 2) * 36] = va.z;
    dstc[(kh * 8 + 3) * 36] = va.w;
    dstc[(kh * 8 + 4) * 36] = vb.x;
    dstc[(kh * 8 + 5) * 36] = vb.y;
    dstc[(kh * 8 + 6) * 36] = vb.z;
    dstc[(kh * 8 + 7) * 36] = vb.w;

    const float* ps = ptt + (size_t)kbase * EE;
    const float4 q0 = *(const float4*)(ps + lane * 4);
    const float4 q1 = *(const float4*)(ps + 256 + lane * 4);
    const float4 q2 = *(const float4*)(ps + 512 + lane * 4);
    const float4 q3 = *(const float4*)(ps + 768 + lane * 4);
    float* pd = &pt[w][0][0] + lane * 4;
    *(float4*)(pd)       = q0;
    *(float4*)(pd + 256) = q1;
    *(float4*)(pd + 512) = q2;
    *(float4*)(pd + 768) = q3;
  }

  for (int c = 0; c < 8; ++c) {   // 8 chunks x 16 k = 128 k
    const int cur = c & 1;
    // ---- prefetch next chunk's x + proto (consumed after the k-loop) ----
    float4 na, nb, r0, r1, r2, r3;
    if (c + 1 < 8) {
      const float* xs = xb + (size_t)toks * DD + kbase + (c + 1) * 16 + kh * 8;
      na = *(const float4*)(xs);
      nb = *(const float4*)(xs + 4);
      const float* ps = ptt + (size_t)(kbase + (c + 1) * 16) * EE;
      r0 = *(const float4*)(ps + lane * 4);
      r1 = *(const float4*)(ps + 256 + lane * 4);
      r2 = *(const float4*)(ps + 512 + lane * 4);
      r3 = *(const float4*)(ps + 768 + lane * 4);
    }
    // ---- 16 k-steps: ds_read x-frag + ds_read proto + 32 fmac ----
    const float* xc = &xt[w][cur][0][tg * 4];
    const float* pc = &pt[w][0][eg * 8];
#pragma unroll
    for (int kk = 0; kk < 16; ++kk) {
      const float4 xf = *(const float4*)(xc + kk * 36);
      const float4 p0 = *(const float4*)(pc + kk * 64);
      const float4 p1 = *(const float4*)(pc + kk * 64 + 4);
      FMA4(acc0[0], xf.x, p0) FMA4(acc1[0], xf.x, p1)
      FMA4(acc0[1], xf.y, p0) FMA4(acc1[1], xf.y, p1)
      FMA4(acc0[2], xf.z, p0) FMA4(acc1[2], xf.z, p1)
      FMA4(acc0[3], xf.w, p0) FMA4(acc1[3], xf.w, p1)
    }
    // ---- stage prefetched chunk (pt same buffer; wave-private DS in-order) --
    if (c + 1 < 8) {
      q += SUMSQ4(na) + SUMSQ4(nb);
      float* dstc = &xt[w][cur ^ 1][0][toks];
      dstc[(kh * 8 + 0) * 36] = na.x;
      dstc[(kh * 8 + 1) * 36] = na.y;
      dstc[(kh * 8 + 2) * 36] = na.z;
      dstc[(kh * 8 + 3) * 36] = na.w;
      dstc[(kh * 8 + 4) * 36] = nb.x;
      dstc[(kh * 8 + 5) * 36] = nb.y;
      dstc[(kh * 8 + 6) * 36] = nb.z;
      dstc[(kh * 8 + 7) * 36] = nb.w;
      float* pd = &pt[w][0][0] + lane * 4;
      *(float4*)(pd)       = r0;
      *(float4*)(pd + 256) = r1;
      *(float4*)(pd + 512) = r2;
      *(float4*)(pd + 768) = r3;
    }
  }

  // sumsq: combine the two k-halves of each token; kh==0 lanes publish
  q += __shfl_xor(q, 32);
  if (kh == 0) nq[w][toks] = q;

  // epilogue reduction buffers alias the (now dead) xt region
  float (*B0)[68] = reinterpret_cast<float (*)[68]>(&xt[0][0][0][0]);
  float (*B1)[68] = reinterpret_cast<float (*)[68]>(&xt[0][0][0][0] + 32 * 68);

#define WRB(R)                                                  \
  { _Pragma("unroll") for (int i = 0; i < 4; ++i) {             \
      *(float4*)(&(R)[tg * 4 + i][eg * 8])     = acc0[i];       \
      *(float4*)(&(R)[tg * 4 + i][eg * 8 + 4]) = acc1[i]; } }
#define ADDB(R)                                                 \
  { _Pragma("unroll") for (int i = 0; i < 4; ++i) {             \
      const float4 t0 = *(const float4*)(&(R)[tg * 4 + i][eg * 8]);     \
      const float4 t1 = *(const float4*)(&(R)[tg * 4 + i][eg * 8 + 4]); \
      acc0[i].x += t0.x; acc0[i].y += t0.y;                     \
      acc0[i].z += t0.z; acc0[i].w += t0.w;                     \
      acc1[i].x += t1.x; acc1[i].y += t1.y;                     \
      acc1[i].z += t1.z; acc1[i].w += t1.w; } }

  // deterministic tree over 8 waves: pairwise (w, w+1) -> (w, w+2) -> (w, w+4)
  __syncthreads();
  if (w == 1) WRB(B0)
  if (w == 5) WRB(B1)
  __syncthreads();
  if (w == 0) ADDB(B0)
  if (w == 4) ADDB(B1)
  __syncthreads();
  if (w == 3) WRB(B0)
  if (w == 7) WRB(B1)
  __syncthreads();
  if (w == 2) ADDB(B0)
  if (w == 6) ADDB(B1)
  __syncthreads();
  if (w == 2) WRB(B0)
  if (w == 6) WRB(B1)
  __syncthreads();
  if (w == 0) ADDB(B0)
  if (w == 4) ADDB(B1)
  __syncthreads();
  if (w == 4) WRB(B0)
  __syncthreads();
  if (w == 0) {
    ADDB(B0)
#pragma unroll
    for (int i = 0; i < 4; ++i) {
      const int row = tg * 4 + i;
      const float qs = nq[0][row] + nq[1][row] + nq[2][row] + nq[3][row] +
                       nq[4][row] + nq[5][row] + nq[6][row] + nq[7][row];
      const float inv = 1.0f / fmaxf(sqrtf(qs), EPSV);
      float4 o0, o1;
      o0.x = acc0[i].x * inv; o0.y = acc0[i].y * inv;
      o0.z = acc0[i].z * inv; o0.w = acc0[i].w * inv;
      o1.x = acc1[i].x * inv; o1.y = acc1[i].y * inv;
      o1.z = acc1[i].z * inv; o1.w = acc1[i].w * inv;
      float* dp = dots + ((size_t)b * SS + s0 + row) * EE + eg * 8;
      *(float4*)(dp)     = o0;
      *(float4*)(dp + 4) = o1;
    }
  }
}

// ---- K2: window-3 + top-2 + renorm softmax (array-free, R7-verified) -------
#define T2UP(s, ei)                                            \
  if ((s) > v1) { v2 = v1; i2 = i1; v1 = (s); i1 = (ei); }     \
  else if ((s) > v2) { v2 = (s); i2 = (ei); }

__global__ __launch_bounds__(256) void router_top2(
    const float* __restrict__ dots, float* __restrict__ out) {
  const int gtid = blockIdx.x * 256 + threadIdx.x;  // 0..32767
  const int tok  = gtid >> 1;          // global token
  const int h    = gtid & 1;           // expert half (32 each)
  const int b    = tok >> 11;
  const int sl   = tok & (SS - 1);
  const int r0   = (sl >= 2) ? sl - 2 : 0;   // causal pad: replicate token 0
  const int r1   = (sl >= 1) ? sl - 1 : 0;

  const float* d0 = dots + ((size_t)b * SS + r0) * EE + h * 32;
  const float* d1 = dots + ((size_t)b * SS + r1) * EE + h * 32;
  const float* d2 = dots + ((size_t)b * SS + sl) * EE + h * 32;

  float v1 = -INFINITY, v2 = -INFINITY;
  int i1 = 0, i2 = 0;
#pragma unroll
  for (int qd = 0; qd < 8; ++qd) {
    const float4 a = *(const float4*)(d0 + qd * 4);
    const float4 c = *(const float4*)(d1 + qd * 4);
    const float4 e = *(const float4*)(d2 + qd * 4);
    const int e0 = h * 32 + qd * 4;
    float s;
    s = a.x + c.x + e.x; T2UP(s, e0 + 0)
    s = a.y + c.y + e.y; T2UP(s, e0 + 1)
    s = a.z + c.z + e.z; T2UP(s, e0 + 2)
    s = a.w + c.w + e.w; T2UP(s, e0 + 3)
  }

  {  // merge the two halves (partner lane = lane^1); tie -> lower index
    const float ov1 = __shfl_xor(v1, 1);
    const int   oi1 = __shfl_xor(i1, 1);
    const float ov2 = __shfl_xor(v2, 1);
    const int   oi2 = __shfl_xor(i2, 1);
    const bool o_beats = (ov1 > v1) || (ov1 == v1 && oi1 < i1);
    if (o_beats) {
      const bool v1_beats_o2 = (v1 > ov2) || (v1 == ov2 && i1 < oi2);
      v2 = v1_beats_o2 ? v1 : ov2;
      i2 = v1_beats_o2 ? i1 : oi2;
      v1 = ov1;
      i1 = oi1;
    } else {
      const bool o1_beats_v2 = (ov1 > v2) || (ov1 == v2 && oi1 < i2);
      if (o1_beats_v2) { v2 = ov1; i2 = oi1; }
    }
  }

  if (h == 0) {
    const float ex = expf((v2 - v1) * (1.0f / 3.0f));  // <= 1
    const float w1 = 1.0f / (1.0f + ex);
    const size_t o = (size_t)tok * 2;
    *(float2*)(out + o) = make_float2((float)i1, (float)i2);
    *(float2*)(out + (size_t)BB * SS * 2 + o) = make_float2(w1, ex * w1);
  }
}

extern "C" void kernel_launch(void* const* d_in, const int* in_sizes, int n_in,
                              void* d_out, int out_size, void* d_ws, size_t ws_size,
                              hipStream_t stream) {
  const float* x     = (const float*)d_in[0];
  const float* proto = (const float*)d_in[1];
  // d_in[2] = attn_mask: unused by the reference output path.
  float* out  = (float*)d_out;
  float* ptt  = (float*)d_ws;                          // 256 KiB ptt[d][e]
  float* dots = (float*)((char*)d_ws + (512 << 10));   // 4 MiB normalized dots

  repack_proto<<<dim3(256), dim3(256), 0, stream>>>(proto, ptt);
  router_dots<<<dim3(512), dim3(512), 0, stream>>>(x, ptt, dots);
  router_top2<<<dim3(128), dim3(256), 0, stream>>>(dots, out);
}